// Round 20
// baseline (23.819 us; speedup 1.0000x reference)
//
#include <hip/hip_runtime.h>
#include <hip/hip_bf16.h>
#include <math.h>

#define D 256
#define S 4096
#define BATCH 4
#define RPB 32                    // rows per fused block (2 Mt tiles)
#define NBLK (BATCH * S / RPB)    // 512 fused blocks
#define DT_CUT 4.0f               // R20: 4.5->4.0; omitted mass ~1.7e-3 pre-LN

typedef __attribute__((ext_vector_type(8))) short short8;
typedef __attribute__((ext_vector_type(4))) float f32x4;

#define NEG_HALF_LOG2E (-0.72134752f)   // exp(-0.5 x^2) = exp2(c * x^2)

static __device__ __forceinline__ unsigned short f2bf(float x) {
    union { __hip_bfloat16 b; unsigned short u; } cv;
    cv.b = __float2bfloat16(x);    // HW RNE convert; compiler packs pairs
    return cv.u;
}

// ===========================================================================
// w5 fragment-tiled layout:  w5: tile (et16*8 + kt), elem = lane*8 + ee
//                  (e = et16*16 + (lane&15), d = kt*32 + (lane>>4)*8 + ee)
// Embedding computed on the fly (R13: materialized emb = 64 MB/rep L2-miss).
// Scalar f2bf only (R15: hand-written cvt_pk asm broke correctness).
// R16 structure; DT_CUT narrowed twice (error budget: end-to-end ~4e-4).
// ===========================================================================

// ---------------------------------------------------------------------------
// K1 (tiny): W -> w5 fragment tiles; band-start jcmin for 2 fused blocks.
// ---------------------------------------------------------------------------
__global__ __launch_bounds__(256) void prep_kernel(const float* __restrict__ t,
                                                   const float* __restrict__ W,
                                                   unsigned short* __restrict__ w5,
                                                   int* __restrict__ jcmin_out) {
    int blk = blockIdx.x;      // 256 blocks
    int tid = threadIdx.x;

    {   // W[e][d] -> w5 fragment tiles (row e = blk)
        int e = blk, dd = tid;
        int et16 = e >> 4, l15 = e & 15;
        int kt = dd >> 5, kgg = (dd >> 3) & 3, ee = dd & 7;
        w5[(size_t)((et16 * 8 + kt) * 512) + (kgg * 16 + l15) * 8 + ee]
            = f2bf(W[e * D + dd]);
    }

    // wave 0: band-start searches for fused blocks 2*blk, 2*blk+1
    if (tid < 64) {
#pragma unroll
        for (int s = 0; s < 2; ++s) {
            int fb = blk * 2 + s;
            int b2 = fb >> 7;
            int i0 = (fb & 127) * RPB;
            const float* tb2 = t + b2 * S;
            float tcut = tb2[i0] - DT_CUT;
            int lo = 0, hi = i0;                 // invariant: t[hi] >= tcut
            while (hi > lo) {
                int step = ((hi - lo) + 63) >> 6;
                int p = min(lo + tid * step, hi);
                unsigned long long mb = __ballot(tb2[p] < tcut);
                int cnt = __popcll(mb);
                int nlo = (cnt == 0) ? lo : (lo + (cnt - 1) * step + 1);
                int nhi = (cnt == 0) ? nlo : min(lo + cnt * step, hi);
                lo = nlo; hi = nhi;
            }
            if (tid == 0) jcmin_out[fb] = lo >> 5;
        }
    }
}

// ---------------------------------------------------------------------------
// K2: fused band-GEMM (on-the-fly B) + LayerNorm + decoder-GEMM + softplus.
// Block = 32 rows (2 Mt) x 256 d/e, 4 waves; B-fragment sin generation
// shared across both Mt tiles. EXACT R16/R19 structure.
// ---------------------------------------------------------------------------
__global__ __launch_bounds__(256, 2) void fused_kernel(
    const float* __restrict__ t, const unsigned short* __restrict__ w5,
    const int* __restrict__ jcmin_arr,
    const float* __restrict__ gamma, const float* __restrict__ beta,
    const float* __restrict__ w_t, const float* __restrict__ b_t,
    float* __restrict__ out) {
    int bid  = blockIdx.x;
    int blk  = (bid & 7) * (NBLK / 8) + (bid >> 3);   // XCD swizzle (bijective)
    int b    = blk >> 7;                 // 128 blocks per batch
    int i0   = (blk & 127) * RPB;
    int tid  = threadIdx.x;
    int w    = tid >> 6;
    int lane = tid & 63;
    int ln15 = lane & 15;
    int kg   = lane >> 4;
    const float* tb = t + b * S;

    float ti0 = tb[i0 + ln15], ti1 = tb[i0 + 16 + ln15];
    int   ir0 = i0 + ln15,     ir1 = i0 + 16 + ln15;
    int jcmin = jcmin_arr[blk];
    int jcmax = i0 >> 5;                 // diagonal chunk (serves both Mt)

    // per-lane embedding constants: d = w*64 + nt*16 + ln15, k = d>>1
    const float c2 = -0.1038102552f;     // -2*log2(10000)/256
    float cr[4];
#pragma unroll
    for (int nt = 0; nt < 4; ++nt) {
        int d = w * 64 + nt * 16 + ln15;
        cr[nt] = exp2f(c2 * (float)((d >> 1) + 1));
    }
    float phase = (ln15 & 1) ? 1.5707963268f : 0.0f;  // cos = sin(x + pi/2)

    // ---- band GEMM: C[m, d] += scores[m, k] * emb[k, d]  (B on the fly)
    f32x4 acc[2][4];
#pragma unroll
    for (int Mt = 0; Mt < 2; ++Mt)
#pragma unroll
        for (int nt = 0; nt < 4; ++nt) acc[Mt][nt] = (f32x4){0.f, 0.f, 0.f, 0.f};

    for (int jc = jcmin; jc < jcmax; ++jc) {      // fully-causal chunks
        int j0 = jc * 32;
        float4 ta4 = *(const float4*)&tb[j0 + kg * 8];
        float4 tb4 = *(const float4*)&tb[j0 + kg * 8 + 4];
        float tj[8] = {ta4.x, ta4.y, ta4.z, ta4.w, tb4.x, tb4.y, tb4.z, tb4.w};

        union { short8 v; unsigned short u[8]; } a0, a1;
#pragma unroll
        for (int e = 0; e < 8; ++e) {
            float d0 = ti0 - tj[e], d1 = ti1 - tj[e];
            a0.u[e] = f2bf(exp2f(NEG_HALF_LOG2E * d0 * d0));
            a1.u[e] = f2bf(exp2f(NEG_HALF_LOG2E * d1 * d1));
        }
#pragma unroll
        for (int nt = 0; nt < 4; ++nt) {
            union { short8 v; unsigned short u[8]; } bf;
#pragma unroll
            for (int e = 0; e < 8; ++e)
                bf.u[e] = f2bf(__sinf(fmaf(tj[e], cr[nt], phase)));
            acc[0][nt] = __builtin_amdgcn_mfma_f32_16x16x32_bf16(a0.v, bf.v, acc[0][nt], 0, 0, 0);
            acc[1][nt] = __builtin_amdgcn_mfma_f32_16x16x32_bf16(a1.v, bf.v, acc[1][nt], 0, 0, 0);
        }
    }
    {   // peeled diagonal chunk jc == jcmax (causal masks for both Mt)
        int j0 = jcmax * 32;
        float4 ta4 = *(const float4*)&tb[j0 + kg * 8];
        float4 tb4 = *(const float4*)&tb[j0 + kg * 8 + 4];
        float tj[8] = {ta4.x, ta4.y, ta4.z, ta4.w, tb4.x, tb4.y, tb4.z, tb4.w};

        union { short8 v; unsigned short u[8]; } a0, a1;
#pragma unroll
        for (int e = 0; e < 8; ++e) {
            int j = j0 + kg * 8 + e;
            float d0 = ti0 - tj[e], d1 = ti1 - tj[e];
            float s0 = exp2f(NEG_HALF_LOG2E * d0 * d0);
            float s1 = exp2f(NEG_HALF_LOG2E * d1 * d1);
            a0.u[e] = (j <= ir0) ? f2bf(s0) : (unsigned short)0;
            a1.u[e] = (j <= ir1) ? f2bf(s1) : (unsigned short)0;
        }
#pragma unroll
        for (int nt = 0; nt < 4; ++nt) {
            union { short8 v; unsigned short u[8]; } bf;
#pragma unroll
            for (int e = 0; e < 8; ++e)
                bf.u[e] = f2bf(__sinf(fmaf(tj[e], cr[nt], phase)));
            acc[0][nt] = __builtin_amdgcn_mfma_f32_16x16x32_bf16(a0.v, bf.v, acc[0][nt], 0, 0, 0);
            acc[1][nt] = __builtin_amdgcn_mfma_f32_16x16x32_bf16(a1.v, bf.v, acc[1][nt], 0, 0, 0);
        }
    }

    // ---- hoist decoder kt=0 weight frags (independent of LN barriers)
    const unsigned short* wbase = w5 + (size_t)(w * 4 * 8) * 512 + lane * 8;
    short8 w0 = *(const short8*)(wbase + (size_t)(0 * 8) * 512);
    short8 w1 = *(const short8*)(wbase + (size_t)(1 * 8) * 512);
    short8 w2 = *(const short8*)(wbase + (size_t)(2 * 8) * 512);
    short8 w3 = *(const short8*)(wbase + (size_t)(3 * 8) * 512);

    // ---- LayerNorm (row r = Mt*16 + kg*4 + reg; col d = w*64 + nt*16 + ln15)
    __shared__ float2 s_ln[4][RPB];
    __shared__ unsigned short H[RPB][264];       // +8 pad
    __shared__ float s_dec[4][RPB];

#pragma unroll
    for (int Mt = 0; Mt < 2; ++Mt)
#pragma unroll
        for (int reg = 0; reg < 4; ++reg) {
            float s = acc[Mt][0][reg] + acc[Mt][1][reg] + acc[Mt][2][reg] + acc[Mt][3][reg];
            float q = acc[Mt][0][reg] * acc[Mt][0][reg] + acc[Mt][1][reg] * acc[Mt][1][reg]
                    + acc[Mt][2][reg] * acc[Mt][2][reg] + acc[Mt][3][reg] * acc[Mt][3][reg];
#pragma unroll
            for (int m = 1; m < 16; m <<= 1) {
                s += __shfl_xor(s, m);
                q += __shfl_xor(q, m);
            }
            if (ln15 == 0) s_ln[w][Mt * 16 + kg * 4 + reg] = make_float2(s, q);
        }
    __syncthreads();

    float g[4], be[4];
#pragma unroll
    for (int nt = 0; nt < 4; ++nt) {
        g[nt]  = gamma[w * 64 + nt * 16 + ln15];
        be[nt] = beta[w * 64 + nt * 16 + ln15];
    }
#pragma unroll
    for (int Mt = 0; Mt < 2; ++Mt)
#pragma unroll
        for (int reg = 0; reg < 4; ++reg) {
            int r = Mt * 16 + kg * 4 + reg;
            float2 p0 = s_ln[0][r], p1 = s_ln[1][r], p2 = s_ln[2][r], p3 = s_ln[3][r];
            float sum = p0.x + p1.x + p2.x + p3.x;
            float sq  = p0.y + p1.y + p2.y + p3.y;
            float mu  = sum * (1.0f / D);
            float var = fmaxf(sq * (1.0f / D) - mu * mu, 0.0f);
            float rstd = rsqrtf(var + 1e-6f);
#pragma unroll
            for (int nt = 0; nt < 4; ++nt) {
                float h = (acc[Mt][nt][reg] - mu) * rstd * g[nt] + be[nt];
                H[r][w * 64 + nt * 16 + ln15] = f2bf(h);
            }
        }
    __syncthreads();

    // ---- decoder GEMM: C2[m, e] = sum_d H[m, d] * W[e, d], kt pipelined;
    //      W-frags reused across both Mt tiles.
    f32x4 acc2[2][4];
#pragma unroll
    for (int Mt = 0; Mt < 2; ++Mt)
#pragma unroll
        for (int et = 0; et < 4; ++et) acc2[Mt][et] = (f32x4){0.f, 0.f, 0.f, 0.f};

#pragma unroll
    for (int kt = 0; kt < 8; ++kt) {
        short8 nw0, nw1, nw2, nw3;
        if (kt < 7) {
            const unsigned short* p = wbase + (size_t)(kt + 1) * 512;
            nw0 = *(const short8*)(p + (size_t)(0 * 8) * 512);
            nw1 = *(const short8*)(p + (size_t)(1 * 8) * 512);
            nw2 = *(const short8*)(p + (size_t)(2 * 8) * 512);
            nw3 = *(const short8*)(p + (size_t)(3 * 8) * 512);
        }
        short8 a0 = *(const short8*)&H[ln15][kt * 32 + kg * 8];
        short8 a1 = *(const short8*)&H[16 + ln15][kt * 32 + kg * 8];
        acc2[0][0] = __builtin_amdgcn_mfma_f32_16x16x32_bf16(a0, w0, acc2[0][0], 0, 0, 0);
        acc2[0][1] = __builtin_amdgcn_mfma_f32_16x16x32_bf16(a0, w1, acc2[0][1], 0, 0, 0);
        acc2[0][2] = __builtin_amdgcn_mfma_f32_16x16x32_bf16(a0, w2, acc2[0][2], 0, 0, 0);
        acc2[0][3] = __builtin_amdgcn_mfma_f32_16x16x32_bf16(a0, w3, acc2[0][3], 0, 0, 0);
        acc2[1][0] = __builtin_amdgcn_mfma_f32_16x16x32_bf16(a1, w0, acc2[1][0], 0, 0, 0);
        acc2[1][1] = __builtin_amdgcn_mfma_f32_16x16x32_bf16(a1, w1, acc2[1][1], 0, 0, 0);
        acc2[1][2] = __builtin_amdgcn_mfma_f32_16x16x32_bf16(a1, w2, acc2[1][2], 0, 0, 0);
        acc2[1][3] = __builtin_amdgcn_mfma_f32_16x16x32_bf16(a1, w3, acc2[1][3], 0, 0, 0);
        w0 = nw0; w1 = nw1; w2 = nw2; w3 = nw3;
    }

    // ---- epilogue: relu -> *w_t -> reduce over e -> softplus
    float wt[4];
#pragma unroll
    for (int et = 0; et < 4; ++et) wt[et] = w_t[w * 64 + et * 16 + ln15];
#pragma unroll
    for (int Mt = 0; Mt < 2; ++Mt)
#pragma unroll
        for (int reg = 0; reg < 4; ++reg) {
            float v = 0.f;
#pragma unroll
            for (int et = 0; et < 4; ++et)
                v = fmaf(fmaxf(acc2[Mt][et][reg], 0.f), wt[et], v);
#pragma unroll
            for (int m = 1; m < 16; m <<= 1) v += __shfl_xor(v, m);
            if (ln15 == 0) s_dec[w][Mt * 16 + kg * 4 + reg] = v;
        }
    __syncthreads();
    if (tid < RPB) {
        float tot = s_dec[0][tid] + s_dec[1][tid] + s_dec[2][tid] + s_dec[3][tid] + b_t[0];
        float o = fmaxf(tot, 0.0f) + log1pf(expf(-fabsf(tot)));   // softplus
        out[(size_t)blk * RPB + tid] = o;
    }
}

// ---------------------------------------------------------------------------
extern "C" void kernel_launch(void* const* d_in, const int* in_sizes, int n_in,
                              void* d_out, int out_size, void* d_ws, size_t ws_size,
                              hipStream_t stream) {
    // inputs: 0 event_type(i32) 1 event_time(f32) 2 arrival_times(f32)
    //         3 W_in 4 w_t 5 b_t 6 ln_gamma 7 ln_beta
    const float* t   = (const float*)d_in[1];
    const float* W   = (const float*)d_in[3];
    const float* wt  = (const float*)d_in[4];
    const float* bt  = (const float*)d_in[5];
    const float* gam = (const float*)d_in[6];
    const float* bet = (const float*)d_in[7];
    float* out = (float*)d_out;

    char* ws = (char*)d_ws;
    unsigned short* w5    = (unsigned short*)ws;                 // 128 KiB
    int*            jcmin = (int*)(ws + (size_t)131072);         // 2 KiB

    prep_kernel<<<dim3(256), dim3(256), 0, stream>>>(t, W, w5, jcmin);
    fused_kernel<<<dim3(NBLK), dim3(256), 0, stream>>>(
        t, w5, jcmin, gam, bet, wt, bt, out);
}

// Round 21
// 22.767 us; speedup vs baseline: 1.0462x; 1.0462x over previous
//
#include <hip/hip_runtime.h>
#include <hip/hip_bf16.h>
#include <math.h>

#define D 256
#define S 4096
#define BATCH 4
#define RPB 32                    // rows per fused block (2 Mt tiles)
#define NBLK (BATCH * S / RPB)    // 512 fused blocks
#define DT_CUT 4.5f               // omitted-score sum ~2e-4 pre-LN (R19-validated)

typedef __attribute__((ext_vector_type(8))) short short8;
typedef __attribute__((ext_vector_type(4))) float f32x4;

static __device__ __forceinline__ unsigned short f2bf(float x) {
    union { __hip_bfloat16 b; unsigned short u; } cv;
    cv.b = __float2bfloat16(x);    // HW RNE convert; compiler packs pairs
    return cv.u;
}

// ===========================================================================
// Best-measured configuration (R19: 22.76 us). Session invariants:
//  - Embedding computed on the fly (R13 counters: materialized emb = 64 MB/rep
//    L2-miss fetch; closed-form sin costs ~4 VALU ops/elem and wins).
//  - w5 fragment-tiled: tile (et16*8 + kt), elem = lane*8 + ee
//      (e = et16*16 + (lane&15), d = kt*32 + (lane>>4)*8 + ee)
//    so every decoder B-fragment is one contiguous coalesced 1KB wave load.
//  - Scalar f2bf only (R15: hand-written v_cvt_pk_bf16_f32 asm broke output).
//  - RPB=32: B-sin generation shared across 2 Mt tiles (R16/R17: kernel is
//    issue-bound on fragment gen; replication x occupancy ~ const across all
//    tested structures, so this simple form is the family optimum).
// ===========================================================================

// ---------------------------------------------------------------------------
// K1 (tiny): W -> w5 fragment tiles; band-start jcmin for 2 fused blocks.
// ---------------------------------------------------------------------------
__global__ __launch_bounds__(256) void prep_kernel(const float* __restrict__ t,
                                                   const float* __restrict__ W,
                                                   unsigned short* __restrict__ w5,
                                                   int* __restrict__ jcmin_out) {
    int blk = blockIdx.x;      // 256 blocks
    int tid = threadIdx.x;

    {   // W[e][d] -> w5 fragment tiles (row e = blk)
        int e = blk, dd = tid;
        int et16 = e >> 4, l15 = e & 15;
        int kt = dd >> 5, kgg = (dd >> 3) & 3, ee = dd & 7;
        w5[(size_t)((et16 * 8 + kt) * 512) + (kgg * 16 + l15) * 8 + ee]
            = f2bf(W[e * D + dd]);
    }

    // wave 0: band-start searches for fused blocks 2*blk, 2*blk+1
    if (tid < 64) {
#pragma unroll
        for (int s = 0; s < 2; ++s) {
            int fb = blk * 2 + s;
            int b2 = fb >> 7;
            int i0 = (fb & 127) * RPB;
            const float* tb2 = t + b2 * S;
            float tcut = tb2[i0] - DT_CUT;
            int lo = 0, hi = i0;                 // invariant: t[hi] >= tcut
            while (hi > lo) {
                int step = ((hi - lo) + 63) >> 6;
                int p = min(lo + tid * step, hi);
                unsigned long long mb = __ballot(tb2[p] < tcut);
                int cnt = __popcll(mb);
                int nlo = (cnt == 0) ? lo : (lo + (cnt - 1) * step + 1);
                int nhi = (cnt == 0) ? nlo : min(lo + cnt * step, hi);
                lo = nlo; hi = nhi;
            }
            if (tid == 0) jcmin_out[fb] = lo >> 5;
        }
    }
}

// ---------------------------------------------------------------------------
// K2: fused band-GEMM (on-the-fly B) + LayerNorm + decoder-GEMM + softplus.
// Block = 32 rows (2 Mt) x 256 d/e, 4 waves; B-fragment sin generation
// shared across both Mt tiles.
// ---------------------------------------------------------------------------
__global__ __launch_bounds__(256, 2) void fused_kernel(
    const float* __restrict__ t, const unsigned short* __restrict__ w5,
    const int* __restrict__ jcmin_arr,
    const float* __restrict__ gamma, const float* __restrict__ beta,
    const float* __restrict__ w_t, const float* __restrict__ b_t,
    float* __restrict__ out) {
    int bid  = blockIdx.x;
    int blk  = (bid & 7) * (NBLK / 8) + (bid >> 3);   // XCD swizzle (bijective)
    int b    = blk >> 7;                 // 128 blocks per batch
    int i0   = (blk & 127) * RPB;
    int tid  = threadIdx.x;
    int w    = tid >> 6;
    int lane = tid & 63;
    int ln15 = lane & 15;
    int kg   = lane >> 4;
    const float* tb = t + b * S;

    float ti0 = tb[i0 + ln15], ti1 = tb[i0 + 16 + ln15];
    int   ir0 = i0 + ln15,     ir1 = i0 + 16 + ln15;
    int jcmin = jcmin_arr[blk];
    int jcmax = i0 >> 5;                 // diagonal chunk (serves both Mt)

    // per-lane embedding constants: d = w*64 + nt*16 + ln15, k = d>>1
    const float c2 = -0.1038102552f;     // -2*log2(10000)/256
    float cr[4];
#pragma unroll
    for (int nt = 0; nt < 4; ++nt) {
        int d = w * 64 + nt * 16 + ln15;
        cr[nt] = exp2f(c2 * (float)((d >> 1) + 1));
    }
    float phase = (ln15 & 1) ? 1.5707963268f : 0.0f;  // cos = sin(x + pi/2)

    // ---- band GEMM: C[m, d] += scores[m, k] * emb[k, d]  (B on the fly)
    f32x4 acc[2][4];
#pragma unroll
    for (int Mt = 0; Mt < 2; ++Mt)
#pragma unroll
        for (int nt = 0; nt < 4; ++nt) acc[Mt][nt] = (f32x4){0.f, 0.f, 0.f, 0.f};

    for (int jc = jcmin; jc < jcmax; ++jc) {      // fully-causal chunks
        int j0 = jc * 32;
        float4 ta4 = *(const float4*)&tb[j0 + kg * 8];
        float4 tb4 = *(const float4*)&tb[j0 + kg * 8 + 4];
        float tj[8] = {ta4.x, ta4.y, ta4.z, ta4.w, tb4.x, tb4.y, tb4.z, tb4.w};

        union { short8 v; unsigned short u[8]; } a0, a1;
#pragma unroll
        for (int e = 0; e < 8; ++e) {
            float d0 = ti0 - tj[e], d1 = ti1 - tj[e];
            a0.u[e] = f2bf(__expf(-0.5f * d0 * d0));
            a1.u[e] = f2bf(__expf(-0.5f * d1 * d1));
        }
#pragma unroll
        for (int nt = 0; nt < 4; ++nt) {
            union { short8 v; unsigned short u[8]; } bf;
#pragma unroll
            for (int e = 0; e < 8; ++e)
                bf.u[e] = f2bf(__sinf(fmaf(tj[e], cr[nt], phase)));
            acc[0][nt] = __builtin_amdgcn_mfma_f32_16x16x32_bf16(a0.v, bf.v, acc[0][nt], 0, 0, 0);
            acc[1][nt] = __builtin_amdgcn_mfma_f32_16x16x32_bf16(a1.v, bf.v, acc[1][nt], 0, 0, 0);
        }
    }
    {   // peeled diagonal chunk jc == jcmax (causal masks for both Mt)
        int j0 = jcmax * 32;
        float4 ta4 = *(const float4*)&tb[j0 + kg * 8];
        float4 tb4 = *(const float4*)&tb[j0 + kg * 8 + 4];
        float tj[8] = {ta4.x, ta4.y, ta4.z, ta4.w, tb4.x, tb4.y, tb4.z, tb4.w};

        union { short8 v; unsigned short u[8]; } a0, a1;
#pragma unroll
        for (int e = 0; e < 8; ++e) {
            int j = j0 + kg * 8 + e;
            float d0 = ti0 - tj[e], d1 = ti1 - tj[e];
            float s0 = __expf(-0.5f * d0 * d0), s1 = __expf(-0.5f * d1 * d1);
            a0.u[e] = (j <= ir0) ? f2bf(s0) : (unsigned short)0;
            a1.u[e] = (j <= ir1) ? f2bf(s1) : (unsigned short)0;
        }
#pragma unroll
        for (int nt = 0; nt < 4; ++nt) {
            union { short8 v; unsigned short u[8]; } bf;
#pragma unroll
            for (int e = 0; e < 8; ++e)
                bf.u[e] = f2bf(__sinf(fmaf(tj[e], cr[nt], phase)));
            acc[0][nt] = __builtin_amdgcn_mfma_f32_16x16x32_bf16(a0.v, bf.v, acc[0][nt], 0, 0, 0);
            acc[1][nt] = __builtin_amdgcn_mfma_f32_16x16x32_bf16(a1.v, bf.v, acc[1][nt], 0, 0, 0);
        }
    }

    // ---- hoist decoder kt=0 weight frags (independent of LN barriers)
    const unsigned short* wbase = w5 + (size_t)(w * 4 * 8) * 512 + lane * 8;
    short8 w0 = *(const short8*)(wbase + (size_t)(0 * 8) * 512);
    short8 w1 = *(const short8*)(wbase + (size_t)(1 * 8) * 512);
    short8 w2 = *(const short8*)(wbase + (size_t)(2 * 8) * 512);
    short8 w3 = *(const short8*)(wbase + (size_t)(3 * 8) * 512);

    // ---- LayerNorm (row r = Mt*16 + kg*4 + reg; col d = w*64 + nt*16 + ln15)
    __shared__ float2 s_ln[4][RPB];
    __shared__ unsigned short H[RPB][264];       // +8 pad
    __shared__ float s_dec[4][RPB];

#pragma unroll
    for (int Mt = 0; Mt < 2; ++Mt)
#pragma unroll
        for (int reg = 0; reg < 4; ++reg) {
            float s = acc[Mt][0][reg] + acc[Mt][1][reg] + acc[Mt][2][reg] + acc[Mt][3][reg];
            float q = acc[Mt][0][reg] * acc[Mt][0][reg] + acc[Mt][1][reg] * acc[Mt][1][reg]
                    + acc[Mt][2][reg] * acc[Mt][2][reg] + acc[Mt][3][reg] * acc[Mt][3][reg];
#pragma unroll
            for (int m = 1; m < 16; m <<= 1) {
                s += __shfl_xor(s, m);
                q += __shfl_xor(q, m);
            }
            if (ln15 == 0) s_ln[w][Mt * 16 + kg * 4 + reg] = make_float2(s, q);
        }
    __syncthreads();

    float g[4], be[4];
#pragma unroll
    for (int nt = 0; nt < 4; ++nt) {
        g[nt]  = gamma[w * 64 + nt * 16 + ln15];
        be[nt] = beta[w * 64 + nt * 16 + ln15];
    }
#pragma unroll
    for (int Mt = 0; Mt < 2; ++Mt)
#pragma unroll
        for (int reg = 0; reg < 4; ++reg) {
            int r = Mt * 16 + kg * 4 + reg;
            float2 p0 = s_ln[0][r], p1 = s_ln[1][r], p2 = s_ln[2][r], p3 = s_ln[3][r];
            float sum = p0.x + p1.x + p2.x + p3.x;
            float sq  = p0.y + p1.y + p2.y + p3.y;
            float mu  = sum * (1.0f / D);
            float var = fmaxf(sq * (1.0f / D) - mu * mu, 0.0f);
            float rstd = rsqrtf(var + 1e-6f);
#pragma unroll
            for (int nt = 0; nt < 4; ++nt) {
                float h = (acc[Mt][nt][reg] - mu) * rstd * g[nt] + be[nt];
                H[r][w * 64 + nt * 16 + ln15] = f2bf(h);
            }
        }
    __syncthreads();

    // ---- decoder GEMM: C2[m, e] = sum_d H[m, d] * W[e, d], kt pipelined;
    //      W-frags reused across both Mt tiles.
    f32x4 acc2[2][4];
#pragma unroll
    for (int Mt = 0; Mt < 2; ++Mt)
#pragma unroll
        for (int et = 0; et < 4; ++et) acc2[Mt][et] = (f32x4){0.f, 0.f, 0.f, 0.f};

#pragma unroll
    for (int kt = 0; kt < 8; ++kt) {
        short8 nw0, nw1, nw2, nw3;
        if (kt < 7) {
            const unsigned short* p = wbase + (size_t)(kt + 1) * 512;
            nw0 = *(const short8*)(p + (size_t)(0 * 8) * 512);
            nw1 = *(const short8*)(p + (size_t)(1 * 8) * 512);
            nw2 = *(const short8*)(p + (size_t)(2 * 8) * 512);
            nw3 = *(const short8*)(p + (size_t)(3 * 8) * 512);
        }
        short8 a0 = *(const short8*)&H[ln15][kt * 32 + kg * 8];
        short8 a1 = *(const short8*)&H[16 + ln15][kt * 32 + kg * 8];
        acc2[0][0] = __builtin_amdgcn_mfma_f32_16x16x32_bf16(a0, w0, acc2[0][0], 0, 0, 0);
        acc2[0][1] = __builtin_amdgcn_mfma_f32_16x16x32_bf16(a0, w1, acc2[0][1], 0, 0, 0);
        acc2[0][2] = __builtin_amdgcn_mfma_f32_16x16x32_bf16(a0, w2, acc2[0][2], 0, 0, 0);
        acc2[0][3] = __builtin_amdgcn_mfma_f32_16x16x32_bf16(a0, w3, acc2[0][3], 0, 0, 0);
        acc2[1][0] = __builtin_amdgcn_mfma_f32_16x16x32_bf16(a1, w0, acc2[1][0], 0, 0, 0);
        acc2[1][1] = __builtin_amdgcn_mfma_f32_16x16x32_bf16(a1, w1, acc2[1][1], 0, 0, 0);
        acc2[1][2] = __builtin_amdgcn_mfma_f32_16x16x32_bf16(a1, w2, acc2[1][2], 0, 0, 0);
        acc2[1][3] = __builtin_amdgcn_mfma_f32_16x16x32_bf16(a1, w3, acc2[1][3], 0, 0, 0);
        w0 = nw0; w1 = nw1; w2 = nw2; w3 = nw3;
    }

    // ---- epilogue: relu -> *w_t -> reduce over e -> softplus
    float wt[4];
#pragma unroll
    for (int et = 0; et < 4; ++et) wt[et] = w_t[w * 64 + et * 16 + ln15];
#pragma unroll
    for (int Mt = 0; Mt < 2; ++Mt)
#pragma unroll
        for (int reg = 0; reg < 4; ++reg) {
            float v = 0.f;
#pragma unroll
            for (int et = 0; et < 4; ++et)
                v = fmaf(fmaxf(acc2[Mt][et][reg], 0.f), wt[et], v);
#pragma unroll
            for (int m = 1; m < 16; m <<= 1) v += __shfl_xor(v, m);
            if (ln15 == 0) s_dec[w][Mt * 16 + kg * 4 + reg] = v;
        }
    __syncthreads();
    if (tid < RPB) {
        float tot = s_dec[0][tid] + s_dec[1][tid] + s_dec[2][tid] + s_dec[3][tid] + b_t[0];
        float o = fmaxf(tot, 0.0f) + log1pf(expf(-fabsf(tot)));   // softplus
        out[(size_t)blk * RPB + tid] = o;
    }
}

// ---------------------------------------------------------------------------
extern "C" void kernel_launch(void* const* d_in, const int* in_sizes, int n_in,
                              void* d_out, int out_size, void* d_ws, size_t ws_size,
                              hipStream_t stream) {
    // inputs: 0 event_type(i32) 1 event_time(f32) 2 arrival_times(f32)
    //         3 W_in 4 w_t 5 b_t 6 ln_gamma 7 ln_beta
    const float* t   = (const float*)d_in[1];
    const float* W   = (const float*)d_in[3];
    const float* wt  = (const float*)d_in[4];
    const float* bt  = (const float*)d_in[5];
    const float* gam = (const float*)d_in[6];
    const float* bet = (const float*)d_in[7];
    float* out = (float*)d_out;

    char* ws = (char*)d_ws;
    unsigned short* w5    = (unsigned short*)ws;                 // 128 KiB
    int*            jcmin = (int*)(ws + (size_t)131072);         // 2 KiB

    prep_kernel<<<dim3(256), dim3(256), 0, stream>>>(t, W, w5, jcmin);
    fused_kernel<<<dim3(NBLK), dim3(256), 0, stream>>>(
        t, w5, jcmin, gam, bet, wt, bt, out);
}